// Round 3
// baseline (699.347 us; speedup 1.0000x reference)
//
#include <hip/hip_runtime.h>
#include <hip/hip_bf16.h>
#include <hip/hip_cooperative_groups.h>

namespace cg = cooperative_groups;

#define NN 1024
#define FF 128
#define NSPLIT 8

// One cooperative kernel, 256 blocks x 256 threads, 4 phases with grid.sync():
//   P1: zp[s][f][m] = sum_{n in split s} U[n,m]*x[n,f]     (split-K GEMM, TN)
//   P2: zt[m][f]    = filters[f][m][m] * sum_s zp[s][f][m] (reduce + diag scale)
//   P3: op[s][f][n] = sum_{m in split s} zt[m][f]*U[n,m]   (split-K GEMM)
//   P4: out[f][n]   = sum_s op[s][f][n]
// All intermediates are L2/L3-resident (<= 4 MiB each); fusion removes 3
// dispatch round-trips vs the 4-kernel version.
__global__ __launch_bounds__(256) void fused_gcl(const float* __restrict__ U,
                                                 const float* __restrict__ x,
                                                 const float* __restrict__ filters,
                                                 float* __restrict__ zp,
                                                 float* __restrict__ zt,
                                                 float* __restrict__ op,
                                                 float* __restrict__ out) {
    cg::grid_group grid = cg::this_grid();

    __shared__ float As[16][34];    // GEMM A tile (pad 34 for P3 transpose-write)
    __shared__ float Bs[16][128];   // GEMM B tile

    const int tid = threadIdx.x;
    const int bid = blockIdx.x;

    // ---------------- Phase 1: gemm1 (32 m-tiles x 8 n-splits) ----------------
    {
        const int tm = tid & 15;
        const int tf = tid >> 4;
        const int m0 = (bid & 31) * 32;
        const int s  = bid >> 5;
        const int n0 = s * 128;

        float acc[2][8];
#pragma unroll
        for (int i = 0; i < 2; ++i)
#pragma unroll
            for (int j = 0; j < 8; ++j) acc[i][j] = 0.f;

        const int ka = tid >> 4, ma = (tid & 15) * 2;
        const int kb = tid >> 5, fb = (tid & 31) * 4;

        for (int kt = 0; kt < 8; ++kt) {
            const int nb = n0 + kt * 16;
            *(float2*)&As[ka][ma] = *(const float2*)&U[(size_t)(nb + ka) * NN + m0 + ma];
            *(float4*)&Bs[kb][fb]     = *(const float4*)&x[(size_t)(nb + kb) * FF + fb];
            *(float4*)&Bs[kb + 8][fb] = *(const float4*)&x[(size_t)(nb + kb + 8) * FF + fb];
            __syncthreads();
#pragma unroll
            for (int k = 0; k < 16; ++k) {
                const float2 a  = *(const float2*)&As[k][tm * 2];
                const float4 b0 = *(const float4*)&Bs[k][tf * 8];
                const float4 b1 = *(const float4*)&Bs[k][tf * 8 + 4];
                acc[0][0] += a.x * b0.x; acc[0][1] += a.x * b0.y;
                acc[0][2] += a.x * b0.z; acc[0][3] += a.x * b0.w;
                acc[0][4] += a.x * b1.x; acc[0][5] += a.x * b1.y;
                acc[0][6] += a.x * b1.z; acc[0][7] += a.x * b1.w;
                acc[1][0] += a.y * b0.x; acc[1][1] += a.y * b0.y;
                acc[1][2] += a.y * b0.z; acc[1][3] += a.y * b0.w;
                acc[1][4] += a.y * b1.x; acc[1][5] += a.y * b1.y;
                acc[1][6] += a.y * b1.z; acc[1][7] += a.y * b1.w;
            }
            __syncthreads();
        }

#pragma unroll
        for (int i = 0; i < 2; ++i) {
            const int m = m0 + tm * 2 + i;
#pragma unroll
            for (int j = 0; j < 8; ++j) {
                const int f = tf * 8 + j;
                zp[((size_t)s * FF + f) * NN + m] = acc[i][j];
            }
        }
    }
    grid.sync();

    // ---------------- Phase 2: reduce over splits + diag scale ----------------
    {
#pragma unroll
        for (int r = 0; r < 2; ++r) {
            const int idx = bid * 512 + r * 256 + tid;  // idx = f*1024 + m
            const int f = idx >> 10;
            const int m = idx & 1023;
            float s = 0.f;
#pragma unroll
            for (int sp = 0; sp < NSPLIT; ++sp)
                s += zp[((size_t)sp * FF + f) * NN + m];
            const float d = filters[(size_t)f * (NN * NN) + (size_t)m * (NN + 1)];
            zt[(size_t)m * FF + f] = s * d;
        }
    }
    grid.sync();

    // ---------------- Phase 3: gemm2 (32 n-tiles x 8 m-splits) ----------------
    {
        const int tn = tid & 15;
        const int tf = tid >> 4;
        const int n0 = (bid & 31) * 32;
        const int s  = bid >> 5;
        const int m0 = s * 128;

        float acc[2][8];
#pragma unroll
        for (int i = 0; i < 2; ++i)
#pragma unroll
            for (int j = 0; j < 8; ++j) acc[i][j] = 0.f;

        const int na = tid >> 3, kk = (tid & 7) * 2;
        const int kb = tid >> 5, fb = (tid & 31) * 4;

        for (int kt = 0; kt < 8; ++kt) {
            const int mb = m0 + kt * 16;
            const float2 v = *(const float2*)&U[(size_t)(n0 + na) * NN + mb + kk];
            As[kk][na]     = v.x;
            As[kk + 1][na] = v.y;
            *(float4*)&Bs[kb][fb]     = *(const float4*)&zt[(size_t)(mb + kb) * FF + fb];
            *(float4*)&Bs[kb + 8][fb] = *(const float4*)&zt[(size_t)(mb + kb + 8) * FF + fb];
            __syncthreads();
#pragma unroll
            for (int k = 0; k < 16; ++k) {
                const float2 a  = *(const float2*)&As[k][tn * 2];
                const float4 b0 = *(const float4*)&Bs[k][tf * 8];
                const float4 b1 = *(const float4*)&Bs[k][tf * 8 + 4];
                acc[0][0] += a.x * b0.x; acc[0][1] += a.x * b0.y;
                acc[0][2] += a.x * b0.z; acc[0][3] += a.x * b0.w;
                acc[0][4] += a.x * b1.x; acc[0][5] += a.x * b1.y;
                acc[0][6] += a.x * b1.z; acc[0][7] += a.x * b1.w;
                acc[1][0] += a.y * b0.x; acc[1][1] += a.y * b0.y;
                acc[1][2] += a.y * b0.z; acc[1][3] += a.y * b0.w;
                acc[1][4] += a.y * b1.x; acc[1][5] += a.y * b1.y;
                acc[1][6] += a.y * b1.z; acc[1][7] += a.y * b1.w;
            }
            __syncthreads();
        }

#pragma unroll
        for (int i = 0; i < 2; ++i) {
            const int n = n0 + tn * 2 + i;
#pragma unroll
            for (int j = 0; j < 8; ++j) {
                const int f = tf * 8 + j;
                op[((size_t)s * FF + f) * NN + n] = acc[i][j];
            }
        }
    }
    grid.sync();

    // ---------------- Phase 4: reduce out over splits ----------------
    {
#pragma unroll
        for (int r = 0; r < 2; ++r) {
            const int idx = bid * 512 + r * 256 + tid;  // idx = f*1024 + n
            float s = 0.f;
#pragma unroll
            for (int sp = 0; sp < NSPLIT; ++sp)
                s += op[(size_t)sp * FF * NN + idx];
            out[idx] = s;
        }
    }
}

// ---------------------------------------------------------------------------
extern "C" void kernel_launch(void* const* d_in, const int* in_sizes, int n_in,
                              void* d_out, int out_size, void* d_ws, size_t ws_size,
                              hipStream_t stream) {
    const float* x       = (const float*)d_in[0];   // (1024, 128)
    const float* U       = (const float*)d_in[1];   // (1024, 1024)
    const float* filters = (const float*)d_in[2];   // (128, 1024, 1024), diagonal

    float* out = (float*)d_out;                     // (128, 1024)
    float* zp  = (float*)d_ws;                      // [8][128][1024]
    float* zt  = zp + (size_t)NSPLIT * FF * NN;     // [1024][128]
    float* op  = zt + (size_t)NN * FF;              // [8][128][1024]

    void* args[] = {(void*)&U, (void*)&x, (void*)&filters,
                    (void*)&zp, (void*)&zt, (void*)&op, (void*)&out};
    hipLaunchCooperativeKernel((const void*)fused_gcl, dim3(256), dim3(256),
                               args, 0, stream);
}

// Round 4
// 596.454 us; speedup vs baseline: 1.1725x; 1.1725x over previous
//
#include <hip/hip_runtime.h>
#include <hip/hip_bf16.h>

#define NN 1024
#define FF 128
#define NSPLIT 16

// 4 plain kernels (cooperative launch measured +100us in this harness — never again).
// Workspace (floats):
//   zp[NSPLIT][FF][NN]  split-K partials of U^T x   (8 MiB)
//   zt[NN][FF]          diag-scaled reduced z        (512 KiB)
//   op[NSPLIT][FF][NN]  split-K partials of out      (8 MiB)
// One writer per slice: no memsets, no atomics.

// ---------------------------------------------------------------------------
// K1: zp[s][f][m] = sum_{n in split s} U[n,m] * x[n,f]
// Tile 32m x 128f, BK=16, split-K over n: 16 splits of 64. grid (32,16)=512.
// ---------------------------------------------------------------------------
__global__ __launch_bounds__(256) void gemm1(const float* __restrict__ U,
                                             const float* __restrict__ x,
                                             float* __restrict__ zp) {
    __shared__ float As[16][32];    // [k][m]
    __shared__ float Bs[16][128];   // [k][f]

    const int tid = threadIdx.x;
    const int tm = tid & 15;
    const int tf = tid >> 4;
    const int m0 = blockIdx.x * 32;
    const int s  = blockIdx.y;
    const int n0 = s * 64;

    float acc[2][8];
#pragma unroll
    for (int i = 0; i < 2; ++i)
#pragma unroll
        for (int j = 0; j < 8; ++j) acc[i][j] = 0.f;

    const int ka = tid >> 4, ma = (tid & 15) * 2;
    const int kb = tid >> 5, fb = (tid & 31) * 4;

    for (int kt = 0; kt < 4; ++kt) {
        const int nb = n0 + kt * 16;
        *(float2*)&As[ka][ma] = *(const float2*)&U[(size_t)(nb + ka) * NN + m0 + ma];
        *(float4*)&Bs[kb][fb]     = *(const float4*)&x[(size_t)(nb + kb) * FF + fb];
        *(float4*)&Bs[kb + 8][fb] = *(const float4*)&x[(size_t)(nb + kb + 8) * FF + fb];
        __syncthreads();
#pragma unroll
        for (int k = 0; k < 16; ++k) {
            const float2 a  = *(const float2*)&As[k][tm * 2];
            const float4 b0 = *(const float4*)&Bs[k][tf * 8];
            const float4 b1 = *(const float4*)&Bs[k][tf * 8 + 4];
            acc[0][0] += a.x * b0.x; acc[0][1] += a.x * b0.y;
            acc[0][2] += a.x * b0.z; acc[0][3] += a.x * b0.w;
            acc[0][4] += a.x * b1.x; acc[0][5] += a.x * b1.y;
            acc[0][6] += a.x * b1.z; acc[0][7] += a.x * b1.w;
            acc[1][0] += a.y * b0.x; acc[1][1] += a.y * b0.y;
            acc[1][2] += a.y * b0.z; acc[1][3] += a.y * b0.w;
            acc[1][4] += a.y * b1.x; acc[1][5] += a.y * b1.y;
            acc[1][6] += a.y * b1.z; acc[1][7] += a.y * b1.w;
        }
        __syncthreads();
    }

#pragma unroll
    for (int i = 0; i < 2; ++i) {
        const int m = m0 + tm * 2 + i;
#pragma unroll
        for (int j = 0; j < 8; ++j) {
            const int f = tf * 8 + j;
            zp[((size_t)s * FF + f) * NN + m] = acc[i][j];
        }
    }
}

// ---------------------------------------------------------------------------
// K2: zt[m][f] = filters[f][m][m] * sum_s zp[s][f][m]
// float4 along m: 128 blocks x 256 threads, coalesced zp reads.
// ---------------------------------------------------------------------------
__global__ __launch_bounds__(256) void reduce_scale(const float* __restrict__ filters,
                                                    const float* __restrict__ zp,
                                                    float* __restrict__ zt) {
    const int idx4 = (blockIdx.x * 256 + threadIdx.x) * 4;  // f*1024 + m, m 4-aligned
    const int f = idx4 >> 10;
    const int m = idx4 & 1023;
    float4 s = make_float4(0.f, 0.f, 0.f, 0.f);
#pragma unroll
    for (int sp = 0; sp < NSPLIT; ++sp) {
        const float4 v = *(const float4*)&zp[((size_t)sp * FF + f) * NN + m];
        s.x += v.x; s.y += v.y; s.z += v.z; s.w += v.w;
    }
    const size_t fbase = (size_t)f * (NN * NN);
#pragma unroll
    for (int i = 0; i < 4; ++i) {
        const float d = filters[fbase + (size_t)(m + i) * (NN + 1)];
        const float v = (i == 0 ? s.x : i == 1 ? s.y : i == 2 ? s.z : s.w);
        zt[(size_t)(m + i) * FF + f] = v * d;
    }
}

// ---------------------------------------------------------------------------
// K3: op[s][f][n] = sum_{m in split s} zt[m][f] * U[n,m]
// Tile 32n x 128f, BK=16, split-K over m: 16 splits of 64. grid (32,16)=512.
// ---------------------------------------------------------------------------
__global__ __launch_bounds__(256) void gemm2(const float* __restrict__ U,
                                             const float* __restrict__ zt,
                                             float* __restrict__ op) {
    __shared__ float As[16][34];    // [k][n] transposed U tile (pad +2)
    __shared__ float Bs[16][128];   // [k][f]

    const int tid = threadIdx.x;
    const int tn = tid & 15;
    const int tf = tid >> 4;
    const int n0 = blockIdx.x * 32;
    const int s  = blockIdx.y;
    const int m0 = s * 64;

    float acc[2][8];
#pragma unroll
    for (int i = 0; i < 2; ++i)
#pragma unroll
        for (int j = 0; j < 8; ++j) acc[i][j] = 0.f;

    const int na = tid >> 3, kk = (tid & 7) * 2;
    const int kb = tid >> 5, fb = (tid & 31) * 4;

    for (int kt = 0; kt < 4; ++kt) {
        const int mb = m0 + kt * 16;
        const float2 v = *(const float2*)&U[(size_t)(n0 + na) * NN + mb + kk];
        As[kk][na]     = v.x;
        As[kk + 1][na] = v.y;
        *(float4*)&Bs[kb][fb]     = *(const float4*)&zt[(size_t)(mb + kb) * FF + fb];
        *(float4*)&Bs[kb + 8][fb] = *(const float4*)&zt[(size_t)(mb + kb + 8) * FF + fb];
        __syncthreads();
#pragma unroll
        for (int k = 0; k < 16; ++k) {
            const float2 a  = *(const float2*)&As[k][tn * 2];
            const float4 b0 = *(const float4*)&Bs[k][tf * 8];
            const float4 b1 = *(const float4*)&Bs[k][tf * 8 + 4];
            acc[0][0] += a.x * b0.x; acc[0][1] += a.x * b0.y;
            acc[0][2] += a.x * b0.z; acc[0][3] += a.x * b0.w;
            acc[0][4] += a.x * b1.x; acc[0][5] += a.x * b1.y;
            acc[0][6] += a.x * b1.z; acc[0][7] += a.x * b1.w;
            acc[1][0] += a.y * b0.x; acc[1][1] += a.y * b0.y;
            acc[1][2] += a.y * b0.z; acc[1][3] += a.y * b0.w;
            acc[1][4] += a.y * b1.x; acc[1][5] += a.y * b1.y;
            acc[1][6] += a.y * b1.z; acc[1][7] += a.y * b1.w;
        }
        __syncthreads();
    }

#pragma unroll
    for (int i = 0; i < 2; ++i) {
        const int n = n0 + tn * 2 + i;
#pragma unroll
        for (int j = 0; j < 8; ++j) {
            const int f = tf * 8 + j;
            op[((size_t)s * FF + f) * NN + n] = acc[i][j];
        }
    }
}

// ---------------------------------------------------------------------------
// K4: out[f][n] = sum_s op[s][f][n] — float4, fully coalesced. 128 blocks.
// ---------------------------------------------------------------------------
__global__ __launch_bounds__(256) void reduce_out(const float* __restrict__ op,
                                                  float* __restrict__ out) {
    const int idx4 = (blockIdx.x * 256 + threadIdx.x) * 4;
    float4 s = make_float4(0.f, 0.f, 0.f, 0.f);
#pragma unroll
    for (int sp = 0; sp < NSPLIT; ++sp) {
        const float4 v = *(const float4*)&op[(size_t)sp * FF * NN + idx4];
        s.x += v.x; s.y += v.y; s.z += v.z; s.w += v.w;
    }
    *(float4*)&out[idx4] = s;
}

// ---------------------------------------------------------------------------
extern "C" void kernel_launch(void* const* d_in, const int* in_sizes, int n_in,
                              void* d_out, int out_size, void* d_ws, size_t ws_size,
                              hipStream_t stream) {
    const float* x       = (const float*)d_in[0];   // (1024, 128)
    const float* U       = (const float*)d_in[1];   // (1024, 1024)
    const float* filters = (const float*)d_in[2];   // (128, 1024, 1024), diagonal

    float* out = (float*)d_out;                     // (128, 1024)
    float* zp  = (float*)d_ws;                      // [16][128][1024]
    float* zt  = zp + (size_t)NSPLIT * FF * NN;     // [1024][128]
    float* op  = zt + (size_t)NN * FF;              // [16][128][1024]

    gemm1<<<dim3(32, NSPLIT), 256, 0, stream>>>(U, x, zp);
    reduce_scale<<<dim3(NN * FF / 1024), 256, 0, stream>>>(filters, zp, zt);
    gemm2<<<dim3(32, NSPLIT), 256, 0, stream>>>(U, zt, op);
    reduce_out<<<dim3(NN * FF / 1024), 256, 0, stream>>>(op, out);
}